// Round 1
// baseline (337.318 us; speedup 1.0000x reference)
//
#include <hip/hip_runtime.h>

#define HW_IMG (224*224)
#define SCALE 0.17677669529663687f   // 1/sqrt(32)

// ---- prep: qh, qk (scaled, [c][h] layout), combined output bias ----
__global__ void prep_q_kernel(const float* __restrict__ query,
                              const float* __restrict__ in_w,
                              const float* __restrict__ in_b,
                              const float* __restrict__ out_w,
                              const float* __restrict__ out_b,
                              const float* __restrict__ aob,
                              float* __restrict__ qk_t,
                              float* __restrict__ cb) {
  __shared__ float qh[256];
  const int t = threadIdx.x;
  float acc = in_b[t];
  for (int c = 0; c < 256; ++c) acc += query[c] * in_w[t*256 + c];
  qh[t] = acc;
  __syncthreads();
  for (int e = t; e < 2048; e += 256) {
    const int c = e >> 3, h = e & 7;
    float s = 0.f;
    #pragma unroll 8
    for (int d = 0; d < 32; ++d)
      s += qh[h*32 + d] * in_w[(256 + h*32 + d)*256 + c];
    qk_t[c*8 + h] = s * SCALE;
  }
  float o = out_b[t];
  for (int k = 0; k < 256; ++k) o += out_w[t*256 + k] * aob[k];
  cb[t] = o;
}

// ---- prep: wv^T and (out_w @ attn_out_w)^T ----
__global__ void prep_w_kernel(const float* __restrict__ in_w,
                              const float* __restrict__ aw,
                              const float* __restrict__ out_w,
                              float* __restrict__ wvT,
                              float* __restrict__ cwT) {
  const int o = blockIdx.x, t = threadIdx.x;
  wvT[t*256 + o] = in_w[(512 + o)*256 + t];
  float a = 0.f;
  #pragma unroll 4
  for (int k = 0; k < 256; ++k) a += out_w[o*256 + k] * aw[k*256 + t];  // out_w row uniform -> s_load
  cwT[t*256 + o] = a;
}

// ---- main: one block per patch ----
__global__ __launch_bounds__(256, 4) void attnpool_main(
    const float* __restrict__ X,
    const float* __restrict__ in_b,
    const float* __restrict__ qk_t,
    const float* __restrict__ wvT,
    const float* __restrict__ cwT,
    const float* __restrict__ cb,
    float* __restrict__ out) {
  __shared__ float smem[28*260 + 196*8];
  float* const Xc = smem;            // [28][260] chunk staging
  float* const W2 = smem + 28*260;   // [196][8] attn weights
  float* const Sl = smem;            // [8][200] scores (overlay on Xc)
  float* const P  = smem;            // [8][256] pooled (overlay on Xc)
  float* const CT = smem + 2048;     // [256] ctx (overlay on Xc tail)

  const int tid = threadIdx.x;
  const int bid = blockIdx.x;
  const int n = (bid & 7) * 256 + (bid >> 3);      // XCD-aware swizzle (2048 % 8 == 0)
  const int b = n >> 8, rem = n & 255, pi = rem >> 4, pj = rem & 15;
  const float* __restrict__ xb = X + (size_t)b * 256 * HW_IMG;
  const int base_sp = pi*14*224 + pj*14;

  // ---- phase A: scores, straight from global, qk via uniform (scalar) loads ----
  if (tid < 196) {
    const int sp = base_sp + (tid/14)*224 + (tid % 14);
    float s0=0,s1=0,s2=0,s3=0,s4=0,s5=0,s6=0,s7=0;
    const float4* __restrict__ qk4 = (const float4*)qk_t;
    #pragma unroll 8
    for (int c = 0; c < 256; ++c) {
      const float xv = xb[(size_t)c*HW_IMG + sp];
      const float4 qa = qk4[2*c];
      const float4 qb = qk4[2*c + 1];
      s0 += xv*qa.x; s1 += xv*qa.y; s2 += xv*qa.z; s3 += xv*qa.w;
      s4 += xv*qb.x; s5 += xv*qb.y; s6 += xv*qb.z; s7 += xv*qb.w;
    }
    Sl[0*200+tid]=s0; Sl[1*200+tid]=s1; Sl[2*200+tid]=s2; Sl[3*200+tid]=s3;
    Sl[4*200+tid]=s4; Sl[5*200+tid]=s5; Sl[6*200+tid]=s6; Sl[7*200+tid]=s7;
  }
  __syncthreads();

  // ---- softmax: 8 groups of 32 lanes, one head each ----
  {
    const int g = tid >> 5, ln = tid & 31;
    float m = -1e30f;
    for (int i = ln; i < 196; i += 32) m = fmaxf(m, Sl[g*200 + i]);
    #pragma unroll
    for (int o = 16; o; o >>= 1) m = fmaxf(m, __shfl_xor(m, o, 32));
    float s = 0.f;
    for (int i = ln; i < 196; i += 32) s += __expf(Sl[g*200 + i] - m);
    #pragma unroll
    for (int o = 16; o; o >>= 1) s += __shfl_xor(s, o, 32);
    const float inv = 1.f / s;
    for (int i = ln; i < 196; i += 32) W2[i*8 + g] = __expf(Sl[g*200 + i] - m) * inv;
  }

  // ---- phase B: chunked re-read -> LDS -> pooled[h][c] ----
  const int hp = tid >> 6;            // wave -> head pair (2hp, 2hp+1)
  const int lq = (tid & 63) * 4;      // lane -> channel quad
  float a00=0,a01=0,a02=0,a03=0,a10=0,a11=0,a12=0,a13=0;
  for (int ch = 0; ch < 7; ++ch) {
    const int l0 = ch * 28;
    __syncthreads();
    #pragma unroll
    for (int it = 0; it < 14; ++it) {
      const int e = it*256 + tid;           // 3584 float2 elems: (c, row-pair)
      const int c = e / 14;
      const int p = e - c*14;
      const int r = 2*p;
      const int l = l0 + r;
      const int lr = l / 14;
      const int sp = base_sp + lr*224 + (l - lr*14);
      const float2 v = *(const float2*)(xb + (size_t)c*HW_IMG + sp);
      Xc[r*260 + c]     = v.x;
      Xc[(r+1)*260 + c] = v.y;
    }
    __syncthreads();
    #pragma unroll 7
    for (int r = 0; r < 28; ++r) {
      const float2 w  = *(const float2*)&W2[(l0 + r)*8 + 2*hp];   // wave-uniform broadcast
      const float4 x4 = *(const float4*)&Xc[r*260 + lq];          // conflict-free b128
      a00 += w.x*x4.x; a01 += w.x*x4.y; a02 += w.x*x4.z; a03 += w.x*x4.w;
      a10 += w.y*x4.x; a11 += w.y*x4.y; a12 += w.y*x4.z; a13 += w.y*x4.w;
    }
  }
  __syncthreads();
  *(float4*)&P[(2*hp)*256 + lq]   = make_float4(a00,a01,a02,a03);
  *(float4*)&P[(2*hp+1)*256 + lq] = make_float4(a10,a11,a12,a13);
  __syncthreads();

  // ---- phase C: ctx = wv_h @ pooled_h + bv ; out = cw @ ctx + cb ----
  {
    const int h = tid >> 5;
    float a = in_b[512 + tid];
    #pragma unroll 4
    for (int c = 0; c < 256; ++c) a += wvT[c*256 + tid] * P[h*256 + c];
    CT[tid] = a;
  }
  __syncthreads();
  {
    float o = cb[tid];
    #pragma unroll 4
    for (int k = 0; k < 256; ++k) o += cwT[k*256 + tid] * CT[k];
    out[(((size_t)b*256 + tid)*16 + pi)*16 + pj] = o;
  }
}

extern "C" void kernel_launch(void* const* d_in, const int* in_sizes, int n_in,
                              void* d_out, int out_size, void* d_ws, size_t ws_size,
                              hipStream_t stream) {
  const float* X    = (const float*)d_in[0];
  const float* q    = (const float*)d_in[1];
  const float* in_w = (const float*)d_in[2];
  const float* in_b = (const float*)d_in[3];
  const float* aw   = (const float*)d_in[4];
  const float* aob  = (const float*)d_in[5];
  const float* ow   = (const float*)d_in[6];
  const float* ob   = (const float*)d_in[7];
  float* out = (float*)d_out;

  float* wsf  = (float*)d_ws;
  float* qk_t = wsf;                 // 2048 floats
  float* cb   = wsf + 2048;          // 256
  float* wvT  = wsf + 4096;          // 65536
  float* cwT  = wsf + 4096 + 65536;  // 65536

  hipLaunchKernelGGL(prep_q_kernel, dim3(1),    dim3(256), 0, stream,
                     q, in_w, in_b, ow, ob, aob, qk_t, cb);
  hipLaunchKernelGGL(prep_w_kernel, dim3(256),  dim3(256), 0, stream,
                     in_w, aw, ow, wvT, cwT);
  hipLaunchKernelGGL(attnpool_main, dim3(2048), dim3(256), 0, stream,
                     X, in_b, qk_t, wvT, cwT, cb, out);
}